// Round 4
// baseline (2812.262 us; speedup 1.0000x reference)
//
#include <hip/hip_runtime.h>
#include <stdint.h>

// ProgressiveVQ: 8-stage residual VQ, T=131072 rows, D=256, K=1024 codewords/stage.
// out[0:T*D] = recon ; out[T*D..+8] = per-stage MSE (= mean(residual_i^2)).
//
//   vq_prep   : fp32 CB -> bf16 copy, FULL-DEPTH swizzled (byte ^ (cw&31)<<4,
//               bijective in the 512B row) + ||c||^2 table.
//   vq_search : R1 geometry (proven no-spill: 4 waves/block, 64 rows/wave as
//               TWO 32-row m-tiles, 2 blocks/CU) + SUPER-CHUNK schedule:
//                 * ONE barrier + ONE vmcnt wait per 2 chunks (64 codewords,
//                   128 MFMA/SIMD/period) — halves sync count vs R1.
//                 * separate acc regs for sub-chunk A and B (4 x f32x16,
//                   ~240 regs/wave total, fits 2 waves/SIMD): no WAR between
//                   pack-A and MFMA-B, so the scheduler overlaps pack-A's
//                   VALU under MFMA-B issue and hides acc-A drain.
//                 * prefetch issued at TOP of period (right after barrier)
//                   for the NEXT period's buffer pair (freed by the barrier
//                   just passed) -> a full period (~4-6k cyc) of flight time;
//                   top-of-period wait is vmcnt(0) (only own staging is ever
//                   outstanding there).
//                 * acc zero-init; -||c||^2/2 deferred to pack; fmax-only
//                   running argmax with index packed in low 10 mantissa bits.
//               bf16-carried residual (argmin near-ties only; validated
//               earlier, absmax <=4.5e-3). ||r||^2 recursion gives MSE free.
//   vq_recon  : recon = sum of 8 chosen bf16 codewords (error ~1.6e-5).

#define T_ROWS   131072
#define DIM      256
#define NSTAGE   8
#define NCB      1024
#define WROWS    64             // rows per wave (2 m-tiles of 32)
#define BLK_ROWS 256            // rows per block (4 waves)
#define NTHREADS 256
#define CHUNK_CW 32             // codewords per chunk (16 KiB)
#define NCHUNK   (NCB / CHUNK_CW)          // 32 chunks/stage
#define NPER     (NCHUNK / 2)              // 16 periods/stage (2 chunks each)
#define CHUNK_BYTES (CHUNK_CW * 512)       // 16384
#define NBUF     4

// d_ws layout
#define WS_CB_BYTES    (NSTAGE * NCB * 512)            // bf16 codebooks, swizzled, 4 MiB
#define WS_CNORM_OFF   WS_CB_BYTES
#define WS_CNORM_BYTES (NSTAGE * NCB * 4)
#define WS_MSE_OFF     (WS_CNORM_OFF + WS_CNORM_BYTES)
#define WS_IDX_OFF     (WS_MSE_OFF + 64)               // u16[NSTAGE][T_ROWS], 2 MiB

typedef __attribute__((ext_vector_type(8)))  short  s16x8;
typedef __attribute__((ext_vector_type(8)))  __bf16 bf16x8;
typedef __attribute__((ext_vector_type(4)))  float  f32x4;
typedef __attribute__((ext_vector_type(16))) float  f32x16;

__device__ __forceinline__ unsigned short f2bf(float f) {
  union { float f; unsigned u; } v; v.f = f;
  unsigned r = v.u + 0x7FFFu + ((v.u >> 16) & 1u);   // RNE
  return (unsigned short)(r >> 16);
}

// ---------------------------------------------------------------------------
// Preprocess: fp32 codebooks -> bf16 swizzled copy + ||c||^2.
// ---------------------------------------------------------------------------
__global__ void vq_prep(const float* __restrict__ CB, char* __restrict__ wscb,
                        float* __restrict__ cnorm) {
  const int tid = threadIdx.x;
  const int cwl = tid >> 5;            // 0..7 codeword within block
  const int j   = tid & 31;            // 16B sub-block (covers d = 8j..8j+7)
  const int cw  = blockIdx.x * 8 + cwl;   // 0..8191 = stage*1024 + c
  const int c   = cw & (NCB - 1);
  const float* src = CB + (size_t)cw * DIM + 8 * j;
  f32x4 a = *(const f32x4*)(src);
  f32x4 b = *(const f32x4*)(src + 4);
  s16x8 h;
#pragma unroll
  for (int e = 0; e < 4; ++e) { h[e] = (short)f2bf(a[e]); h[4 + e] = (short)f2bf(b[e]); }
  float sq = a[0]*a[0] + a[1]*a[1] + a[2]*a[2] + a[3]*a[3]
           + b[0]*b[0] + b[1]*b[1] + b[2]*b[2] + b[3]*b[3];
#pragma unroll
  for (int m = 1; m <= 16; m <<= 1) sq += __shfl_xor(sq, m);   // 32-thread group
  // full-depth swizzle: XOR bits 4..8 with (c&31) -> bijective within 512B row
  *(s16x8*)(wscb + (size_t)cw * 512 + ((16 * j) ^ ((c & 31) << 4))) = h;
  if (j == 0) cnorm[cw] = sq;
}

// ---------------------------------------------------------------------------
// Search kernel. 4 waves/block; wave owns 64 rows as TWO 32-row m-tiles.
// 32x32x16 MFMA layouts: A/B: lane l -> k = 8*(l>>5)+e; A row / B col = l&31.
// C/D: col = l&31, row = (reg&3) + 8*(reg>>2) + 4*(l>>5).
// acc starts at 0; -||c||^2/2 subtracted at pack time so argmin dist ==
// argmax (r.c - cn/2); codeword index packed into low 10 mantissa bits ->
// fmax-only running argmax.
// ---------------------------------------------------------------------------
__global__ __launch_bounds__(NTHREADS, 2)
void vq_search(const float* __restrict__ X,
               const char* __restrict__ wscb, const float* __restrict__ cnorm,
               unsigned short* __restrict__ IDX, float* __restrict__ wsmse) {
  __shared__ __align__(16) char  lds_cb[NBUF][CHUNK_BYTES];  // 4 x 16 KiB ring
  __shared__ __align__(16) float lds_cn[NCB];                // 4 KiB stage cnorm
  __shared__ unsigned short lds_idx[BLK_ROWS];               // 512 B
  __shared__ float lds_n[BLK_ROWS];                          // 1 KiB
  __shared__ float lds_msum[4];                              // 16 B

  const int tid  = threadIdx.x;
  const int wave = tid >> 6;           // 0..3
  const int lane = tid & 63;
  const int c32  = lane & 31;          // A row / B,D col within 32-tile
  const int hi   = lane >> 5;          // k-half (A,B) / row-offset (D)

  const int rowbase = blockIdx.x * BLK_ROWS + wave * WROWS;

  // ---- initial approximate residual = bf16(x), A-fragment layout ----
  // tile t: lane holds row rowbase + t*32 + c32; step s covers dims
  // d = 16*s + 8*hi + e, e=0..7
  bf16x8 af[2][16];
#pragma unroll
  for (int t = 0; t < 2; ++t) {
    const float* px = X + (size_t)(rowbase + t * 32 + c32) * DIM + 8 * hi;
    float s2 = 0.f;
#pragma unroll
    for (int s = 0; s < 16; ++s) {
      f32x4 a = *(const f32x4*)(px + 16 * s);
      f32x4 b = *(const f32x4*)(px + 16 * s + 4);
      bf16x8 tt;
#pragma unroll
      for (int e = 0; e < 4; ++e) {
        tt[e] = (__bf16)a[e]; tt[4 + e] = (__bf16)b[e];
        s2 += a[e] * a[e] + b[e] * b[e];
      }
      af[t][s] = tt;
    }
    // n0 = ||x||^2: lane's partial covers its k-half; pair with lane^32.
    float v = s2 + __shfl_xor(s2, 32);
    if (lane < 32) lds_n[wave * WROWS + t * 32 + c32] = v;
  }

  // ---- prologue: stage-0 cnorm table + period-0 pair (bufs 0,1 = 32KB) ----
  __builtin_amdgcn_global_load_lds(
      (const __attribute__((address_space(1))) char*)((const char*)cnorm + wave * 1024 + lane * 16),
      (__attribute__((address_space(3))) char*)((char*)lds_cn + wave * 1024),
      16, 0, 0);
#pragma unroll
  for (int i = 0; i < 8; ++i) {
    const int seg = (wave * 8 + i) * 1024;
    __builtin_amdgcn_global_load_lds(
        (const __attribute__((address_space(1))) char*)(wscb + seg + lane * 16),
        (__attribute__((address_space(3))) char*)(&lds_cb[0][0] + seg),
        16, 0, 0);
  }

  const int swz = c32 << 4;

#pragma unroll 1
  for (int st = 0; st < NSTAGE; ++st) {
    float mv[2][16];
#pragma unroll
    for (int t = 0; t < 2; ++t)
#pragma unroll
      for (int r = 0; r < 16; ++r) mv[t][r] = -3.402823466e38f;

    const char* stage_cb = wscb + (size_t)st * NCB * 512;

#pragma unroll 1
    for (int p = 0; p < NPER; ++p) {
      // top-of-period: only our own staging (for this period's pair) is ever
      // outstanding here — it was issued a full period (or stage tail) ago.
      asm volatile("s_waitcnt vmcnt(0)" ::: "memory");
      __builtin_amdgcn_sched_barrier(0);
      __builtin_amdgcn_s_barrier();          // single barrier per 2 chunks
      __builtin_amdgcn_sched_barrier(0);

      // prefetch NEXT period's pair into the other buffer pair (freed by the
      // barrier just passed: its last readers were period p-1, and every wave
      // issuing here has passed barrier(p) which follows those reads).
      if (p + 1 < NPER) {
        const char* src = stage_cb + (size_t)(2 * p + 2) * CHUNK_BYTES;
        char* dst = &lds_cb[(2 * p + 2) & 3][0];   // pair is contiguous 32KB
#pragma unroll
        for (int i = 0; i < 8; ++i) {
          const int seg = (wave * 8 + i) * 1024;
          __builtin_amdgcn_global_load_lds(
              (const __attribute__((address_space(1))) char*)(src + seg + lane * 16),
              (__attribute__((address_space(3))) char*)(dst + seg),
              16, 0, 0);
        }
      }

      const int chA = 2 * p, chB = 2 * p + 1;
      // cn reads issued here, consumed only at pack time (~2-4k cyc later)
      const float cnA = lds_cn[chA * CHUNK_CW + c32];
      const float cnB = lds_cn[chB * CHUNK_CW + c32];

      f32x16 aA0, aA1, aB0, aB1;     // separate accs: no WAR between packs/MFMAs
#pragma unroll
      for (int r = 0; r < 16; ++r) { aA0[r] = 0.f; aA1[r] = 0.f; aB0[r] = 0.f; aB1[r] = 0.f; }

      const char* bufA = &lds_cb[chA & 3][0] + c32 * 512;
      const char* bufB = bufA + CHUNK_BYTES;     // chB buf is contiguous next

      __builtin_amdgcn_s_setprio(1);
#pragma unroll
      for (int s = 0; s < 16; ++s) {
        bf16x8 b = *(const bf16x8*)(bufA + ((s * 32 + hi * 16) ^ swz));
        aA0 = __builtin_amdgcn_mfma_f32_32x32x16_bf16(af[0][s], b, aA0, 0, 0, 0);
        aA1 = __builtin_amdgcn_mfma_f32_32x32x16_bf16(af[1][s], b, aA1, 0, 0, 0);
      }
#pragma unroll
      for (int s = 0; s < 16; ++s) {
        bf16x8 b = *(const bf16x8*)(bufB + ((s * 32 + hi * 16) ^ swz));
        aB0 = __builtin_amdgcn_mfma_f32_32x32x16_bf16(af[0][s], b, aB0, 0, 0, 0);
        aB1 = __builtin_amdgcn_mfma_f32_32x32x16_bf16(af[1][s], b, aB1, 0, 0, 0);
      }
      __builtin_amdgcn_s_setprio(0);

      // pack A (scheduler may lift this under MFMA-B issue — independent regs),
      // then pack B. p = (r.c - cn/2), index in low 10 mantissa bits.
      {
        const float cnh = 0.5f * cnA;
        const unsigned col = (unsigned)(chA * CHUNK_CW + c32);
#pragma unroll
        for (int r = 0; r < 16; ++r) {
          union { float f; unsigned u; } p0, p1;
          p0.f = aA0[r] - cnh; p0.u = (p0.u & 0xFFFFFC00u) | col;
          p1.f = aA1[r] - cnh; p1.u = (p1.u & 0xFFFFFC00u) | col;
          mv[0][r] = fmaxf(mv[0][r], p0.f);
          mv[1][r] = fmaxf(mv[1][r], p1.f);
        }
      }
      {
        const float cnh = 0.5f * cnB;
        const unsigned col = (unsigned)(chB * CHUNK_CW + c32);
#pragma unroll
        for (int r = 0; r < 16; ++r) {
          union { float f; unsigned u; } p0, p1;
          p0.f = aB0[r] - cnh; p0.u = (p0.u & 0xFFFFFC00u) | col;
          p1.f = aB1[r] - cnh; p1.u = (p1.u & 0xFFFFFC00u) | col;
          mv[0][r] = fmaxf(mv[0][r], p0.f);
          mv[1][r] = fmaxf(mv[1][r], p1.f);
        }
      }
      // no end-of-period barrier: the pair read next period is protected by
      // the top-of-period barrier (its readers were 2 barriers back).
    }

    // ---- cross-lane argmax + ||r||^2 recursion ----
    // (t,r): row = t*32 + (r&3) + 8*(r>>2) + 4*hi ; reduce over the 32 cols
    float msum = 0.f;
#pragma unroll
    for (int t = 0; t < 2; ++t)
#pragma unroll
      for (int r = 0; r < 16; ++r) {
        float v = mv[t][r];
#pragma unroll
        for (int m = 1; m <= 16; m <<= 1) v = fmaxf(v, __shfl_xor(v, m));
        union { float f; unsigned u; } w; w.f = v;
        const float vtrue = __builtin_bit_cast(float, w.u & 0xFFFFFC00u);
        const int   row   = t * 32 + (r & 3) + 8 * (r >> 2) + 4 * hi;
        const int   wrow  = wave * WROWS + row;
        const float n_new = lds_n[wrow] - 2.0f * vtrue;   // min-dist identity
        msum += n_new;
        if (c32 == 0) {
          lds_n[wrow]   = n_new;
          const int ix = (int)(w.u & 1023u);
          lds_idx[wrow] = (unsigned short)ix;
          IDX[st * T_ROWS + rowbase + row] = (unsigned short)ix;
        }
      }
    // msum uniform within each 32-lane half; halves cover disjoint rows
    msum += __shfl_xor(msum, 32);
    if (lane == 0) lds_msum[wave] = msum;

    if (st != NSTAGE - 1) {
      // ---- approximate af update from bf16 wscb (ranking only) BEFORE the
      //      stage barrier: acc/mv dead here (reg headroom), and its load-
      //      waits drain before next-stage staging issues ----
#pragma unroll
      for (int t = 0; t < 2; ++t) {
        const int idx = (int)lds_idx[wave * WROWS + t * 32 + c32];
        const char* q = stage_cb + (size_t)idx * 512;
        const int swzu = (idx & 31) << 4;
#pragma unroll
        for (int s = 0; s < 16; ++s) {
          bf16x8 qb = *(const bf16x8*)(q + ((s * 32 + hi * 16) ^ swzu));
          bf16x8 tt = af[t][s];
#pragma unroll
          for (int e = 0; e < 8; ++e)
            tt[e] = (__bf16)((float)tt[e] - (float)qb[e]);
          af[t][s] = tt;
        }
      }
    }

    // ---- stage-end barrier: all waves past period-15 compute & cn reads.
    //      Frees cn bank + bufs 0,1 for next-stage staging; orders lds_msum. ----
    __builtin_amdgcn_sched_barrier(0);
    __builtin_amdgcn_s_barrier();
    __builtin_amdgcn_sched_barrier(0);

    // block-level MSE reduction: 1 atomic per block per stage
    if (wave == 0) {
      float v = (lane < 4) ? lds_msum[lane] : 0.f;
      v += __shfl_xor(v, 1);
      v += __shfl_xor(v, 2);
      if (lane == 0) atomicAdd(wsmse + st, v);
    }

    if (st != NSTAGE - 1) {
      // ---- issue next stage's cnorm + period-0 pair (bufs 0,1; last read
      //      in period 14, freed by the stage barrier) ----
      const char* ncb = stage_cb + (size_t)NCB * 512;
      const char* ncn = (const char*)cnorm + (size_t)(st + 1) * NCB * 4;
      __builtin_amdgcn_global_load_lds(
          (const __attribute__((address_space(1))) char*)(ncn + wave * 1024 + lane * 16),
          (__attribute__((address_space(3))) char*)((char*)lds_cn + wave * 1024),
          16, 0, 0);
#pragma unroll
      for (int i = 0; i < 8; ++i) {
        const int seg = (wave * 8 + i) * 1024;
        __builtin_amdgcn_global_load_lds(
            (const __attribute__((address_space(1))) char*)(ncb + seg + lane * 16),
            (__attribute__((address_space(3))) char*)(&lds_cb[0][0] + seg),
            16, 0, 0);
      }
      // barrier before next stage's first read is the p=0 wait+barrier;
      // lds_idx/lds_n slots are per-wave (same-wave DS ordering).
    }
  }
}

// ---------------------------------------------------------------------------
// Recon kernel: OUT[row] = sum of the 8 chosen bf16 codewords.
// Reads only wscb (4 MB, L2-resident) + IDX (2 MB). 8 threads/row.
// ---------------------------------------------------------------------------
__global__ __launch_bounds__(256)
void vq_recon(const char* __restrict__ wscb, const unsigned short* __restrict__ IDX,
              float* __restrict__ OUT) {
  const int tid = threadIdx.x;
  const int row = blockIdx.x * (256 / 8) + (tid >> 3);
  const int g   = tid & 7;             // dims g*32 .. g*32+31

  int idxs[NSTAGE];
#pragma unroll
  for (int st = 0; st < NSTAGE; ++st) idxs[st] = IDX[st * T_ROWS + row];

  float a[32];
#pragma unroll
  for (int d = 0; d < 32; ++d) a[d] = 0.f;

#pragma unroll
  for (int st = 0; st < NSTAGE; ++st) {
    const char* q = wscb + ((size_t)st * NCB + idxs[st]) * 512;
    const int swzu = (idxs[st] & 31) << 4;
#pragma unroll
    for (int k = 0; k < 4; ++k) {
      bf16x8 qb = *(const bf16x8*)(q + ((g * 64 + 16 * k) ^ swzu));
#pragma unroll
      for (int e = 0; e < 8; ++e) a[k * 8 + e] += (float)qb[e];
    }
  }

  float* po = OUT + (size_t)row * DIM + g * 32;
#pragma unroll
  for (int m = 0; m < 8; ++m) {
    f32x4 o = {a[4 * m], a[4 * m + 1], a[4 * m + 2], a[4 * m + 3]};
    *(f32x4*)(po + 4 * m) = o;
  }
}

__global__ void vq_fin(const float* __restrict__ wsmse, float* __restrict__ OUT) {
  const int i = threadIdx.x;
  if (i < NSTAGE) {
    OUT[(size_t)T_ROWS * DIM + i] = wsmse[i] * (1.0f / ((float)T_ROWS * (float)DIM));
  }
}

extern "C" void kernel_launch(void* const* d_in, const int* in_sizes, int n_in,
                              void* d_out, int out_size, void* d_ws, size_t ws_size,
                              hipStream_t stream) {
  (void)in_sizes; (void)n_in; (void)out_size; (void)ws_size;
  const float* X  = (const float*)d_in[0];
  const float* CB = (const float*)d_in[1];
  float* OUT = (float*)d_out;
  char*  wscb  = (char*)d_ws;
  float* cnorm = (float*)((char*)d_ws + WS_CNORM_OFF);
  float* wsmse = (float*)((char*)d_ws + WS_MSE_OFF);
  unsigned short* IDX = (unsigned short*)((char*)d_ws + WS_IDX_OFF);

  hipMemsetAsync(wsmse, 0, NSTAGE * sizeof(float), stream);
  hipLaunchKernelGGL(vq_prep, dim3((NSTAGE * NCB) / 8), dim3(256), 0, stream,
                     CB, wscb, cnorm);
  hipLaunchKernelGGL(vq_search, dim3(T_ROWS / BLK_ROWS), dim3(NTHREADS), 0, stream,
                     X, wscb, cnorm, IDX, wsmse);
  hipLaunchKernelGGL(vq_recon, dim3(T_ROWS / (256 / 8)), dim3(256), 0, stream,
                     wscb, IDX, OUT);
  hipLaunchKernelGGL(vq_fin, dim3(1), dim3(64), 0, stream, wsmse, OUT);
}

// Round 5
// 850.934 us; speedup vs baseline: 3.3049x; 3.3049x over previous
//
#include <hip/hip_runtime.h>
#include <stdint.h>

// ProgressiveVQ: 8-stage residual VQ, T=131072 rows, D=256, K=1024 codewords/stage.
// out[0:T*D] = recon ; out[T*D..+8] = per-stage MSE (= mean(residual_i^2)).
//
// R5 structural change: NO LDS STAGING AT ALL (m169 lesson: staged data that
// L2-fits is pure overhead). vq_prep writes the bf16 codebook directly in
// MFMA B-FRAGMENT ORDER:
//     wsb[stage][g][hi][c32] of bf16x8,  g = ch*16 + s  (1 KB per fragment)
// so vq_search's B-load at (ch,s) is  base + g*1024 + lane*16  — one fully
// coalesced 1 KB global load per instruction, served by L1/L2 (stage slice =
// 512 KB, L2-resident; 16 KB chunk slice shared by 8 waves/CU).
// The whole ring/barrier/vmcnt/global_load_lds machinery is deleted: the
// chunk loop has ZERO barriers. Rolling 4-deep register prefetch (bq[4],
// +16 VGPR — the only register addition over the proven-no-spill R1 set)
// covers L1/L2 latency; the fragment stream is linear across chunks, stages.
//
//   vq_search : 4 waves/block, 64 rows/wave as TWO 32-row m-tiles,
//               mfma_f32_32x32x16_bf16, 2 blocks/CU (reg-capped).
//               acc zero-init; -||c||^2/2 deferred to pack; fmax-only
//               running argmax with index packed in low 10 mantissa bits.
//               bf16-carried residual (argmin near-ties only; validated
//               earlier, absmax <=4.5e-3). ||r||^2 recursion gives MSE free.
//               One __syncthreads per stage (MSE reduce only).
//   vq_recon  : recon = sum of 8 chosen bf16 codewords from the B-layout
//               copy (error ~1.6e-5).

#define T_ROWS   131072
#define DIM      256
#define NSTAGE   8
#define NCB      1024
#define WROWS    64             // rows per wave (2 m-tiles of 32)
#define BLK_ROWS 256            // rows per block (4 waves)
#define NTHREADS 256
#define CHUNK_CW 32             // codewords per chunk
#define NCHUNK   (NCB / CHUNK_CW)          // 32 chunks/stage
#define PF       4              // rolling B-fragment prefetch depth

// d_ws layout (unchanged total footprint ~6.2 MiB)
#define WS_B_BYTES     (NSTAGE * NCB * 512)            // bf16 codebook, B-frag layout, 4 MiB
#define WS_CNORM_OFF   WS_B_BYTES
#define WS_CNORM_BYTES (NSTAGE * NCB * 4)
#define WS_MSE_OFF     (WS_CNORM_OFF + WS_CNORM_BYTES)
#define WS_IDX_OFF     (WS_MSE_OFF + 64)               // u16[NSTAGE][T_ROWS], 2 MiB

typedef __attribute__((ext_vector_type(8)))  short  s16x8;
typedef __attribute__((ext_vector_type(8)))  __bf16 bf16x8;
typedef __attribute__((ext_vector_type(4)))  float  f32x4;
typedef __attribute__((ext_vector_type(16))) float  f32x16;

__device__ __forceinline__ unsigned short f2bf(float f) {
  union { float f; unsigned u; } v; v.f = f;
  unsigned r = v.u + 0x7FFFu + ((v.u >> 16) & 1u);   // RNE
  return (unsigned short)(r >> 16);
}

// ---------------------------------------------------------------------------
// Preprocess: fp32 codebooks -> bf16 copy in B-FRAGMENT layout + ||c||^2.
// Thread (cwl=tid>>5, j=tid&31) handles dims 8j..8j+7 of codeword
// cw = blockIdx*8+cwl.  B-layout address for (c, s=j>>1, hi=j&1):
//   stage*512K + (c>>5)*16384 + s*1024 + hi*512 + (c&31)*16
// ---------------------------------------------------------------------------
__global__ void vq_prep(const float* __restrict__ CB, char* __restrict__ wsb,
                        float* __restrict__ cnorm) {
  const int tid = threadIdx.x;
  const int cwl = tid >> 5;            // 0..7 codeword within block
  const int j   = tid & 31;            // 16B sub-block (covers d = 8j..8j+7)
  const int cw  = blockIdx.x * 8 + cwl;   // 0..8191 = stage*1024 + c
  const int c   = cw & (NCB - 1);
  const int st  = cw >> 10;
  const float* src = CB + (size_t)cw * DIM + 8 * j;
  f32x4 a = *(const f32x4*)(src);
  f32x4 b = *(const f32x4*)(src + 4);
  s16x8 h;
#pragma unroll
  for (int e = 0; e < 4; ++e) { h[e] = (short)f2bf(a[e]); h[4 + e] = (short)f2bf(b[e]); }
  float sq = a[0]*a[0] + a[1]*a[1] + a[2]*a[2] + a[3]*a[3]
           + b[0]*b[0] + b[1]*b[1] + b[2]*b[2] + b[3]*b[3];
#pragma unroll
  for (int m = 1; m <= 16; m <<= 1) sq += __shfl_xor(sq, m);   // 32-thread group
  char* dst = wsb + (size_t)st * NCB * 512
            + (size_t)(c >> 5) * 16384 + (j >> 1) * 1024 + (j & 1) * 512
            + (c & 31) * 16;
  *(s16x8*)dst = h;
  if (j == 0) cnorm[cw] = sq;
}

// ---------------------------------------------------------------------------
// Search kernel. 4 waves/block; wave owns 64 rows as TWO 32-row m-tiles.
// 32x32x16 MFMA layouts: A/B: lane l -> k = 8*(l>>5)+e; A row / B col = l&31.
// C/D: col = l&31, row = (reg&3) + 8*(reg>>2) + 4*(l>>5).
// acc starts at 0; -||c||^2/2 subtracted at pack time so argmin dist ==
// argmax (r.c - cn/2); codeword index packed into low 10 mantissa bits ->
// fmax-only running argmax.
// ---------------------------------------------------------------------------
__global__ __launch_bounds__(NTHREADS, 2)
void vq_search(const float* __restrict__ X,
               const char* __restrict__ wsb, const float* __restrict__ cnorm,
               unsigned short* __restrict__ IDX, float* __restrict__ wsmse) {
  __shared__ unsigned short lds_idx[BLK_ROWS];               // 512 B
  __shared__ float lds_n[BLK_ROWS];                          // 1 KiB
  __shared__ float lds_msum[4];                              // 16 B

  const int tid  = threadIdx.x;
  const int wave = tid >> 6;           // 0..3
  const int lane = tid & 63;
  const int c32  = lane & 31;          // A row / B,D col within 32-tile
  const int hi   = lane >> 5;          // k-half (A,B) / row-offset (D)

  const int rowbase = blockIdx.x * BLK_ROWS + wave * WROWS;

  // ---- initial approximate residual = bf16(x), A-fragment layout ----
  // tile t: lane holds row rowbase + t*32 + c32; step s covers dims
  // d = 16*s + 8*hi + e, e=0..7
  bf16x8 af[2][16];
#pragma unroll
  for (int t = 0; t < 2; ++t) {
    const float* px = X + (size_t)(rowbase + t * 32 + c32) * DIM + 8 * hi;
    float s2 = 0.f;
#pragma unroll
    for (int s = 0; s < 16; ++s) {
      f32x4 a = *(const f32x4*)(px + 16 * s);
      f32x4 b = *(const f32x4*)(px + 16 * s + 4);
      bf16x8 tt;
#pragma unroll
      for (int e = 0; e < 4; ++e) {
        tt[e] = (__bf16)a[e]; tt[4 + e] = (__bf16)b[e];
        s2 += a[e] * a[e] + b[e] * b[e];
      }
      af[t][s] = tt;
    }
    // n0 = ||x||^2: lane's partial covers its k-half; pair with lane^32.
    float v = s2 + __shfl_xor(s2, 32);
    if (lane < 32) lds_n[wave * WROWS + t * 32 + c32] = v;
  }

  // ---- rolling B-fragment prefetch over the linear stream G = 0..4095 ----
  // fragment G lives at wsb + G*1024 + lane*16 (fully coalesced 1KB/wave).
  const char* pb = wsb + (size_t)lane * 16;
  bf16x8 bq[PF];
#pragma unroll
  for (int i = 0; i < PF; ++i)
    bq[i] = *(const bf16x8*)(pb + (size_t)i * 1024);

#pragma unroll 1
  for (int st = 0; st < NSTAGE; ++st) {
    float mv[2][16];
#pragma unroll
    for (int t = 0; t < 2; ++t)
#pragma unroll
      for (int r = 0; r < 16; ++r) mv[t][r] = -3.402823466e38f;

#pragma unroll 1
    for (int ch = 0; ch < NCHUNK; ++ch) {
      // cn read issued at chunk top, consumed only at pack time
      const float cnv = cnorm[st * NCB + ch * CHUNK_CW + c32];

      f32x16 acc0, acc1;
#pragma unroll
      for (int r = 0; r < 16; ++r) { acc0[r] = 0.f; acc1[r] = 0.f; }

      const int g0 = st * 512 + ch * 16;   // linear fragment index of s=0

      __builtin_amdgcn_s_setprio(1);
#pragma unroll
      for (int s = 0; s < 16; ++s) {
        bf16x8 b = bq[s & (PF - 1)];
        // prefetch fragment g0+s+PF (clamped at the last fragment; the
        // clamped loads' values are never consumed)
        int gn = g0 + s + PF;
        if (gn > NSTAGE * 512 - 1) gn = NSTAGE * 512 - 1;
        bq[s & (PF - 1)] = *(const bf16x8*)(pb + (size_t)gn * 1024);
        acc0 = __builtin_amdgcn_mfma_f32_32x32x16_bf16(af[0][s], b, acc0, 0, 0, 0);
        acc1 = __builtin_amdgcn_mfma_f32_32x32x16_bf16(af[1][s], b, acc1, 0, 0, 0);
      }
      __builtin_amdgcn_s_setprio(0);

      // pack: p = (r.c - cn/2) with codeword index in low 10 mantissa bits
      const float cnh = 0.5f * cnv;
      const unsigned col = (unsigned)(ch * CHUNK_CW + c32);
#pragma unroll
      for (int r = 0; r < 16; ++r) {
        union { float f; unsigned u; } p0, p1;
        p0.f = acc0[r] - cnh; p0.u = (p0.u & 0xFFFFFC00u) | col;
        p1.f = acc1[r] - cnh; p1.u = (p1.u & 0xFFFFFC00u) | col;
        mv[0][r] = fmaxf(mv[0][r], p0.f);
        mv[1][r] = fmaxf(mv[1][r], p1.f);
      }
    }

    // ---- cross-lane argmax + ||r||^2 recursion ----
    // (t,r): row = t*32 + (r&3) + 8*(r>>2) + 4*hi ; reduce over the 32 cols
    float msum = 0.f;
#pragma unroll
    for (int t = 0; t < 2; ++t)
#pragma unroll
      for (int r = 0; r < 16; ++r) {
        float v = mv[t][r];
#pragma unroll
        for (int m = 1; m <= 16; m <<= 1) v = fmaxf(v, __shfl_xor(v, m));
        union { float f; unsigned u; } w; w.f = v;
        const float vtrue = __builtin_bit_cast(float, w.u & 0xFFFFFC00u);
        const int   row   = t * 32 + (r & 3) + 8 * (r >> 2) + 4 * hi;
        const int   wrow  = wave * WROWS + row;
        const float n_new = lds_n[wrow] - 2.0f * vtrue;   // min-dist identity
        msum += n_new;
        if (c32 == 0) {
          lds_n[wrow]   = n_new;
          const int ix = (int)(w.u & 1023u);
          lds_idx[wrow] = (unsigned short)ix;
          IDX[st * T_ROWS + rowbase + row] = (unsigned short)ix;
        }
      }
    // msum uniform within each 32-lane half; halves cover disjoint rows
    msum += __shfl_xor(msum, 32);
    if (lane == 0) lds_msum[wave] = msum;

    if (st != NSTAGE - 1) {
      // ---- approximate af update (ranking only) from the B-layout copy.
      //      Lane needs dims d = 16s+8hi+e of codeword idx:
      //      wsb + st*512K + (idx>>5)*16384 + s*1024 + hi*512 + (idx&31)*16
#pragma unroll
      for (int t = 0; t < 2; ++t) {
        const int idx = (int)lds_idx[wave * WROWS + t * 32 + c32];
        const char* q = wsb + (size_t)st * NCB * 512
                      + (size_t)(idx >> 5) * 16384 + hi * 512 + (idx & 31) * 16;
#pragma unroll
        for (int s = 0; s < 16; ++s) {
          bf16x8 qb = *(const bf16x8*)(q + s * 1024);
          bf16x8 tt = af[t][s];
#pragma unroll
          for (int e = 0; e < 8; ++e)
            tt[e] = (__bf16)((float)tt[e] - (float)qb[e]);
          af[t][s] = tt;
        }
      }
    }

    // one barrier per stage: orders lds_msum writes before the reduce.
    __syncthreads();

    // block-level MSE reduction: 1 atomic per block per stage
    if (wave == 0) {
      float v = (lane < 4) ? lds_msum[lane] : 0.f;
      v += __shfl_xor(v, 1);
      v += __shfl_xor(v, 2);
      if (lane == 0) atomicAdd(wsmse + st, v);
    }
  }
}

// ---------------------------------------------------------------------------
// Recon kernel: OUT[row] = sum of the 8 chosen bf16 codewords, read from the
// B-layout copy. 8 threads/row; thread g covers dims g*32..g*32+31:
//   dim d = g*32 + k*8  ->  s = 2g + (k>>1), hi = k&1
//   offset = (idx>>5)*16384 + s*1024 + hi*512 + (idx&31)*16
// ---------------------------------------------------------------------------
__global__ __launch_bounds__(256)
void vq_recon(const char* __restrict__ wsb, const unsigned short* __restrict__ IDX,
              float* __restrict__ OUT) {
  const int tid = threadIdx.x;
  const int row = blockIdx.x * (256 / 8) + (tid >> 3);
  const int g   = tid & 7;             // dims g*32 .. g*32+31

  int idxs[NSTAGE];
#pragma unroll
  for (int st = 0; st < NSTAGE; ++st) idxs[st] = IDX[st * T_ROWS + row];

  float a[32];
#pragma unroll
  for (int d = 0; d < 32; ++d) a[d] = 0.f;

#pragma unroll
  for (int st = 0; st < NSTAGE; ++st) {
    const char* q = wsb + (size_t)st * NCB * 512
                  + (size_t)(idxs[st] >> 5) * 16384 + (idxs[st] & 31) * 16;
#pragma unroll
    for (int k = 0; k < 4; ++k) {
      const int s  = 2 * g + (k >> 1);
      const int h2 = (k & 1);
      bf16x8 qb = *(const bf16x8*)(q + s * 1024 + h2 * 512);
#pragma unroll
      for (int e = 0; e < 8; ++e) a[k * 8 + e] += (float)qb[e];
    }
  }

  float* po = OUT + (size_t)row * DIM + g * 32;
#pragma unroll
  for (int m = 0; m < 8; ++m) {
    f32x4 o = {a[4 * m], a[4 * m + 1], a[4 * m + 2], a[4 * m + 3]};
    *(f32x4*)(po + 4 * m) = o;
  }
}

__global__ void vq_fin(const float* __restrict__ wsmse, float* __restrict__ OUT) {
  const int i = threadIdx.x;
  if (i < NSTAGE) {
    OUT[(size_t)T_ROWS * DIM + i] = wsmse[i] * (1.0f / ((float)T_ROWS * (float)DIM));
  }
}

extern "C" void kernel_launch(void* const* d_in, const int* in_sizes, int n_in,
                              void* d_out, int out_size, void* d_ws, size_t ws_size,
                              hipStream_t stream) {
  (void)in_sizes; (void)n_in; (void)out_size; (void)ws_size;
  const float* X  = (const float*)d_in[0];
  const float* CB = (const float*)d_in[1];
  float* OUT = (float*)d_out;
  char*  wsb   = (char*)d_ws;
  float* cnorm = (float*)((char*)d_ws + WS_CNORM_OFF);
  float* wsmse = (float*)((char*)d_ws + WS_MSE_OFF);
  unsigned short* IDX = (unsigned short*)((char*)d_ws + WS_IDX_OFF);

  hipMemsetAsync(wsmse, 0, NSTAGE * sizeof(float), stream);
  hipLaunchKernelGGL(vq_prep, dim3((NSTAGE * NCB) / 8), dim3(256), 0, stream,
                     CB, wsb, cnorm);
  hipLaunchKernelGGL(vq_search, dim3(T_ROWS / BLK_ROWS), dim3(NTHREADS), 0, stream,
                     X, wsb, cnorm, IDX, wsmse);
  hipLaunchKernelGGL(vq_recon, dim3(T_ROWS / (256 / 8)), dim3(256), 0, stream,
                     wsb, IDX, OUT);
  hipLaunchKernelGGL(vq_fin, dim3(1), dim3(64), 0, stream, wsmse, OUT);
}